// Round 16
// baseline (1588.267 us; speedup 1.0000x reference)
//
#include <hip/hip_runtime.h>
#include <math.h>

#define T_SEQ 12
// B=1024, NG=32, G=32, E=64, H=128, PP=512, BOT=1024, MLPD=1024

typedef __bf16 bf16x8 __attribute__((ext_vector_type(8)));
typedef float f32x4 __attribute__((ext_vector_type(4)));
typedef unsigned short u16x8 __attribute__((ext_vector_type(8)));

static __device__ __forceinline__ unsigned short bf16bits(float x) {
  return __builtin_bit_cast(unsigned short, (__bf16)x);
}
static __device__ __forceinline__ bf16x8 asbf(u16x8 v) {
  return __builtin_bit_cast(bf16x8, v);
}

// Workspace layout (float offsets)
enum : int {
  OFF_LP    = 0,        // [1024,2]
  OFF_DIN   = 2048,     // [1024,64]
  OFF_C     = 198656,   // [1024,128]
  OFF_HDEC  = 329728,   // [1024,128]
  OFF_WC    = 460800,   // [2,512]
  OFF_BC    = 461824,   // [512]
  OFF_PW    = 462336,   // [1024,512]
  OFF_AA    = 986624,   // [1024,512]
  OFF_WP2T  = 1510912,  // [1024,512] bf16
  OFF_WM1T  = 1773056,  // [1024,1152] bf16
  OFF_HCATB = 2362880,  // [1024,1152] bf16 (h | pool)
  OFF_WM2TB = 2952704,  // [128,1024] bf16
  OFF_MIDB  = 3018240,  // [1024,1024] bf16
  OFF_WIHT  = 3542528,  // [64,512] f32 (W_ih^T)
  OFF_WHHT  = 3575296,  // [128,512] f32 (W_hh^T)
  OFF_WFRAG = 3640832   // [1024 frags][64 lanes][8] bf16 = 131072 floats
};                      // end 3771904 floats = 15.1 MB

// XOR swizzle: permute 16B slots within each 128B group by row&7
#define SWZP(byte, row) ((byte) ^ (((row) & 7) << 4))

__global__ __launch_bounds__(256) void k_setup(
    const float* __restrict__ last_pos, const float* __restrict__ lpr,
    const float* __restrict__ dh, const float* __restrict__ dc,
    const float* __restrict__ W_emb, const float* __restrict__ b_emb,
    float* __restrict__ lp, float* __restrict__ din,
    float* __restrict__ h_dec, float* __restrict__ c) {
  int idx = blockIdx.x * 256 + threadIdx.x;  // 0..131071
  if (idx < 2048) lp[idx] = last_pos[idx];
  h_dec[idx] = dh[idx];
  c[idx] = dc[idx];
  if (idx < 65536) {
    int b = idx >> 6, e = idx & 63;
    din[idx] = lpr[b*2] * W_emb[e] + lpr[b*2+1] * W_emb[64+e] + b_emb[e];
  }
}

__global__ __launch_bounds__(256) void k_wc(
    const float* __restrict__ W_sp, const float* __restrict__ b_sp,
    const float* __restrict__ W_pp1, const float* __restrict__ b_pp1,
    float* __restrict__ Wc, float* __restrict__ bc) {
  int n = blockIdx.x * 256 + threadIdx.x;
  if (n >= 512) return;
  float a0 = 0.f, a1 = 0.f, ab = 0.f;
#pragma unroll 8
  for (int k = 0; k < 64; k++) {
    float w = W_pp1[k*512 + n];
    a0 += W_sp[k] * w;
    a1 += W_sp[64+k] * w;
    ab += b_sp[k] * w;
  }
  Wc[n] = a0; Wc[512+n] = a1; bc[n] = ab + b_pp1[n];
}

// Transpose + convert fp32 [R][C] -> bf16 [C][R]
__global__ __launch_bounds__(256) void k_tcvt(
    const float* __restrict__ src, unsigned short* __restrict__ dst,
    int R, int C) {
  __shared__ float t[32][33];
  const int bx = blockIdx.x * 32, by = blockIdx.y * 32;
  const int tx = threadIdx.x & 31, ty = threadIdx.x >> 5;
#pragma unroll
  for (int i = 0; i < 32; i += 8) t[ty+i][tx] = src[(size_t)(by+ty+i)*C + bx+tx];
  __syncthreads();
#pragma unroll
  for (int i = 0; i < 32; i += 8)
    dst[(size_t)(bx+ty+i)*R + by+tx] = bf16bits(t[tx][ty+i]);
}

// Transpose fp32 [R][C] -> fp32 [C][R]
__global__ __launch_bounds__(256) void k_t32(
    const float* __restrict__ src, float* __restrict__ dst, int R, int C) {
  __shared__ float t[32][33];
  const int bx = blockIdx.x * 32, by = blockIdx.y * 32;
  const int tx = threadIdx.x & 31, ty = threadIdx.x >> 5;
#pragma unroll
  for (int i = 0; i < 32; i += 8) t[ty+i][tx] = src[(size_t)(by+ty+i)*C + bx+tx];
  __syncthreads();
#pragma unroll
  for (int i = 0; i < 32; i += 8)
    dst[(size_t)(bx+ty+i)*R + by+tx] = t[tx][ty+i];
}

// Re-arrange Wp2t [1024n][512k] into MFMA B-fragment order:
// Wfrag[fid][lane][8], fid = nbb*16 + kstep.
__global__ __launch_bounds__(256) void k_frag(
    const unsigned short* __restrict__ Wp2t, unsigned short* __restrict__ Wfrag) {
  const int tid = blockIdx.x * 256 + threadIdx.x;  // 0..65535
  const int fid = tid >> 6, l = tid & 63;
  const int nbb = fid >> 4, ks = fid & 15;
  u16x8 v = *(const u16x8*)(Wp2t + (size_t)(nbb*16 + (l & 15))*512 +
                            ks*32 + (l >> 4)*8);
  *(u16x8*)(Wfrag + (size_t)tid*8) = v;
}

// Fused LSTM + h2pos + pool-A-prep: 4 batch rows/block, 512 threads, 256 blocks.
__global__ __launch_bounds__(512) void k_step1(
    float* __restrict__ din, const float* __restrict__ h_dec,
    float* __restrict__ cst, unsigned short* __restrict__ hcatB,
    float* __restrict__ lp, float* __restrict__ pred,
    const float* __restrict__ Wiht, const float* __restrict__ b_ih,
    const float* __restrict__ Whht, const float* __restrict__ b_hh,
    const float* __restrict__ W_h2p, const float* __restrict__ b_h2p,
    const float* __restrict__ W_emb, const float* __restrict__ b_emb,
    const float* __restrict__ W1b, const float* __restrict__ Wc,
    const float* __restrict__ bc,
    float* __restrict__ PW, float* __restrict__ Aa, int t) {
  const int b0 = blockIdx.x * 4;
  const int tid = threadIdx.x;
  __shared__ float xh[4*192];
  __shared__ float gl[4*512];
  __shared__ float hbuf[4*128];
  __shared__ float relS[8], curS[8];

  for (int i = tid; i < 768; i += 512) {
    int r = i / 192, k = i - r*192;
    xh[i] = (k < 64) ? din[(b0+r)*64 + k] : h_dec[(b0+r)*128 + k - 64];
  }
  __syncthreads();
  {
    const int n = tid;
    float bias = b_ih[n] + b_hh[n];
    float acc[4] = {bias, bias, bias, bias};
#pragma unroll 8
    for (int k = 0; k < 64; k++) {
      float wv = Wiht[k*512 + n];
#pragma unroll
      for (int r = 0; r < 4; r++) acc[r] += xh[r*192 + k] * wv;
    }
#pragma unroll 8
    for (int k = 0; k < 128; k++) {
      float wv = Whht[k*512 + n];
#pragma unroll
      for (int r = 0; r < 4; r++) acc[r] += xh[r*192 + 64 + k] * wv;
    }
#pragma unroll
    for (int r = 0; r < 4; r++) gl[r*512 + n] = acc[r];
  }
  __syncthreads();
  {
    int r = tid >> 7, hh = tid & 127;
    float ig = gl[r*512 + hh],       fg = gl[r*512 + 128 + hh];
    float gg = gl[r*512 + 256 + hh], og = gl[r*512 + 384 + hh];
    ig = 1.f/(1.f+expf(-ig)); fg = 1.f/(1.f+expf(-fg));
    gg = tanhf(gg);           og = 1.f/(1.f+expf(-og));
    int row = b0 + r;
    float c2 = fg * cst[row*128 + hh] + ig * gg;
    float h2 = og * tanhf(c2);
    cst[row*128 + hh] = c2;
    hbuf[r*128 + hh] = h2;
    hcatB[(size_t)row*1152 + hh] = bf16bits(h2);
  }
  __syncthreads();
  if (tid < 128) {
    int r = tid >> 5, col = (tid >> 4) & 1, l16 = tid & 15;
    float s = 0.f;
    for (int k = l16; k < 128; k += 16) s += hbuf[r*128 + k] * W_h2p[k*2 + col];
#pragma unroll
    for (int off = 8; off > 0; off >>= 1) s += __shfl_xor(s, off);
    if (l16 == 0) {
      float rel = s + b_h2p[col];
      float old = lp[(b0+r)*2 + col];
      relS[r*2 + col] = rel;
      curS[r*2 + col] = old + rel;
      lp[(b0+r)*2 + col] = old + rel;
      pred[t*2048 + (b0+r)*2 + col] = rel;
    }
  }
  __syncthreads();
  if (tid < 256) {
    int r = tid >> 6, e = tid & 63;
    din[(b0+r)*64 + e] = relS[r*2]*W_emb[e] + relS[r*2+1]*W_emb[64+e] + b_emb[e];
  }
  {
    const int n = tid;
    float acc[4] = {0.f, 0.f, 0.f, 0.f};
#pragma unroll 4
    for (int k = 0; k < 128; k++) {
      float wv = W1b[k*512 + n];
#pragma unroll
      for (int r = 0; r < 4; r++) acc[r] += hbuf[r*128 + k] * wv;
    }
    float wc0 = Wc[n], wc1 = Wc[512+n], bcv = bc[n];
#pragma unroll
    for (int r = 0; r < 4; r++) {
      float pw = curS[r*2]*wc0 + curS[r*2+1]*wc1;
      PW[(size_t)(b0+r)*512 + n] = pw;
      Aa[(size_t)(b0+r)*512 + n] = acc[r] + pw + bcv;
    }
  }
}

// --- Pool GEMM v10: A-resident 128KB LDS; B fragment-direct from global
// with DEPTH-4 circular register prefetch queue; ZERO barriers in main loop.
// All blocks sweep Wfrag in identical order -> L2-hot; 4-step prefetch
// (~840 cyc) covers L2-miss/L3 latency (~600 cyc) that killed pool6's depth-1.
__global__ __launch_bounds__(512) void k_pool10(
    const float* __restrict__ Aa, const float* __restrict__ PW,
    const unsigned short* __restrict__ Wfrag, const float* __restrict__ bp2,
    unsigned short* __restrict__ hcatB) {
  const int bid = blockIdx.x;
  const int mt = (bid >> 3) & 7;
  const int g  = (bid & 7) + ((bid >> 6) << 3);
  const int tid = threadIdx.x, lane = tid & 63, w = tid >> 6;
  const int wr = w >> 2, wc = w & 3;     // 2m x 4n waves, wave tile 64m x 64n
  const int l15 = lane & 15, lhi = lane >> 4;
  __shared__ __align__(128) char As[131072];  // [128 rows][1024B] swizzled

  // Build A tile (rows m = ii*32 + j, i = mt*4+ii): conflict-free wave rows.
  {
    const int ke = lane * 8;
#pragma unroll 4
    for (int rr = 0; rr < 16; rr++) {
      const int r = rr * 8 + w;
      const int j = r & 31, ii = r >> 5;
      const float* aRow = Aa + (size_t)(g*32 + j)*512 + ke;
      const float* pRow = PW + (size_t)(g*32 + mt*4 + ii)*512 + ke;
      float4 a0 = *(const float4*)aRow;
      float4 a1 = *(const float4*)(aRow + 4);
      float4 p0 = *(const float4*)pRow;
      float4 p1 = *(const float4*)(pRow + 4);
      bf16x8 y;
      y[0] = (__bf16)fmaxf(a0.x - p0.x, 0.f);
      y[1] = (__bf16)fmaxf(a0.y - p0.y, 0.f);
      y[2] = (__bf16)fmaxf(a0.z - p0.z, 0.f);
      y[3] = (__bf16)fmaxf(a0.w - p0.w, 0.f);
      y[4] = (__bf16)fmaxf(a1.x - p1.x, 0.f);
      y[5] = (__bf16)fmaxf(a1.y - p1.y, 0.f);
      y[6] = (__bf16)fmaxf(a1.z - p1.z, 0.f);
      y[7] = (__bf16)fmaxf(a1.w - p1.w, 0.f);
      *(bf16x8*)(As + SWZP(r*1024 + lane*16, r)) = y;
    }
  }
  __syncthreads();

  // B prefetch queue: bq[slot][nf], slot = step & 3.
  // frag addr for step q (nt=q>>4, k0=q&15), frag nf:
  //   Wfrag + ((nt*16 + wc*4 + nf)*16 + k0)*512 + lane*8
  const int nbase = wc * 4;   // wave's first nb within each 16-nb group
  u16x8 bq[4][4];
#pragma unroll
  for (int d = 0; d < 4; d++)
#pragma unroll
    for (int nf = 0; nf < 4; nf++)
      bq[d][nf] = *(const u16x8*)(Wfrag +
          ((size_t)((nbase + nf)*16 + d))*512 + lane*8);

  for (int nt = 0; nt < 4; nt++) {
    f32x4 acc[4][4] = {};
#pragma unroll
    for (int k0 = 0; k0 < 16; k0++) {
      const int slot = k0 & 3;
      // consume this step's B frags
      bf16x8 bfr[4];
#pragma unroll
      for (int nf = 0; nf < 4; nf++) bfr[nf] = asbf(bq[slot][nf]);
      // A frags from LDS
      bf16x8 af[4];
#pragma unroll
      for (int mf = 0; mf < 4; mf++) {
        const int row = wr*64 + mf*16 + l15;
        af[mf] = *(const bf16x8*)(As + SWZP(row*1024 + k0*64 + lhi*16, row));
      }
      // refill slot with step q+4
      const int q4 = nt*16 + k0 + 4;
      if (q4 < 64) {
        const int nt4 = q4 >> 4, k4 = q4 & 15;
#pragma unroll
        for (int nf = 0; nf < 4; nf++)
          bq[slot][nf] = *(const u16x8*)(Wfrag +
              ((size_t)((nt4*16 + nbase + nf)*16 + k4))*512 + lane*8);
      }
      // MFMA
#pragma unroll
      for (int mf = 0; mf < 4; mf++)
#pragma unroll
        for (int nf = 0; nf < 4; nf++)
          acc[mf][nf] = __builtin_amdgcn_mfma_f32_16x16x32_bf16(
              af[mf], bfr[nf], acc[mf][nf], 0, 0, 0);
    }
    // epilogue: max over j, bias, relu -> hcatB pool columns
#pragma unroll
    for (int isub = 0; isub < 2; isub++)
#pragma unroll
      for (int nf = 0; nf < 4; nf++) {
        f32x4 v0 = acc[isub*2][nf], v1 = acc[isub*2 + 1][nf];
        float mx = fmaxf(fmaxf(fmaxf(v0[0], v0[1]), fmaxf(v0[2], v0[3])),
                         fmaxf(fmaxf(v1[0], v1[1]), fmaxf(v1[2], v1[3])));
        mx = fmaxf(mx, __shfl_xor(mx, 16));
        mx = fmaxf(mx, __shfl_xor(mx, 32));
        if (lane < 16) {
          const int n = nt*256 + wc*64 + nf*16 + lane;
          const int i = mt*4 + wr*2 + isub;
          hcatB[(size_t)(g*32 + i)*1152 + 128 + n] =
              bf16bits(fmaxf(mx + bp2[n], 0.f));
        }
      }
  }
}

// mid = relu(hcatB @ Wm1t^T + b_m1) -> bf16 midB.
// K-split-wave GEMM (R11): grid (16,16), 256 thr, 4 waves k-split.
__global__ __launch_bounds__(256) void k_m1k(
    const unsigned short* __restrict__ A, const unsigned short* __restrict__ Bw,
    const float* __restrict__ bias, unsigned short* __restrict__ outB) {
  const int nt = blockIdx.x, mt = blockIdx.y;
  const int tid = threadIdx.x, lane = tid & 63, w = tid >> 6;
  const int l15 = lane & 15, lhi = lane >> 4;
  __shared__ __align__(128) char lds[65536];  // buf b: A @ b*32768, B @ +16384
  const unsigned short* aSrc = A  + (size_t)(mt*64)*1152;
  const unsigned short* bSrc = Bw + (size_t)(nt*64)*1152;

  u16x8 rg[8];
#pragma unroll
  for (int p = 0; p < 8; p++) {
    const int u = tid + p*256;
    const int isB = u >> 10, v = u & 1023;
    const int row = v >> 4, slot = v & 15;
    u16x8 val = *(const u16x8*)((isB ? bSrc : aSrc) + (size_t)row*1152 + slot*8);
    *(u16x8*)(lds + isB*16384 + SWZP(row*256 + slot*16, row)) = val;
  }
#pragma unroll
  for (int p = 0; p < 8; p++) {
    const int u = tid + p*256;
    const int isB = u >> 10, v = u & 1023;
    const int row = v >> 4, slot = v & 15;
    rg[p] = *(const u16x8*)((isB ? bSrc : aSrc) + (size_t)row*1152 + 128 + slot*8);
  }
  __syncthreads();

  f32x4 acc[4][4] = {};
  for (int c = 0; c < 9; c++) {
    const int cur = (c & 1) * 32768;
    const int nxt = 32768 - cur;
    if (c < 8) {
#pragma unroll
      for (int p = 0; p < 8; p++) {
        const int u = tid + p*256;
        const int isB = u >> 10, v = u & 1023;
        const int row = v >> 4, slot = v & 15;
        *(u16x8*)(lds + nxt + isB*16384 + SWZP(row*256 + slot*16, row)) = rg[p];
      }
    }
    if (c < 7) {
#pragma unroll
      for (int p = 0; p < 8; p++) {
        const int u = tid + p*256;
        const int isB = u >> 10, v = u & 1023;
        const int row = v >> 4, slot = v & 15;
        rg[p] = *(const u16x8*)((isB ? bSrc : aSrc) + (size_t)row*1152 +
                                (c+2)*128 + slot*8);
      }
    }
    bf16x8 af[4], bf[4];
#pragma unroll
    for (int mf = 0; mf < 4; mf++) {
      const int row = mf*16 + l15;
      af[mf] = *(const bf16x8*)(lds + cur + SWZP(row*256 + w*64 + lhi*16, row));
    }
#pragma unroll
    for (int nf = 0; nf < 4; nf++) {
      const int row = nf*16 + l15;
      bf[nf] = *(const bf16x8*)(lds + cur + 16384 +
                                SWZP(row*256 + w*64 + lhi*16, row));
    }
#pragma unroll
    for (int mf = 0; mf < 4; mf++)
#pragma unroll
      for (int nf = 0; nf < 4; nf++)
        acc[mf][nf] = __builtin_amdgcn_mfma_f32_16x16x32_bf16(
            af[mf], bf[nf], acc[mf][nf], 0, 0, 0);
    __syncthreads();
  }

#pragma unroll
  for (int mf = 0; mf < 4; mf++)
#pragma unroll
    for (int nf = 0; nf < 4; nf++)
      *(f32x4*)(lds + w*16384 + (mf*4 + nf)*1024 + lane*16) = acc[mf][nf];
  __syncthreads();
#pragma unroll
  for (int pi = 0; pi < 4; pi++) {
    const int p = w*4 + pi;
    f32x4 s = *(const f32x4*)(lds + p*1024 + lane*16);
#pragma unroll
    for (int wv = 1; wv < 4; wv++) {
      f32x4 q = *(const f32x4*)(lds + wv*16384 + p*1024 + lane*16);
      s[0] += q[0]; s[1] += q[1]; s[2] += q[2]; s[3] += q[3];
    }
    const int col = nt*64 + (p & 3)*16 + l15;
    const float bv = bias[col];
#pragma unroll
    for (int r = 0; r < 4; r++) {
      const int row = mt*64 + (p >> 2)*16 + lhi*4 + r;
      outB[(size_t)row*1024 + col] = bf16bits(fmaxf(s[r] + bv, 0.f));
    }
  }
}

// h_dec = relu(midB @ Wm2tB^T + b_m2) fp32. K-split-wave (R11).
// At t==T_SEQ-1 also writes out[24576 + row*128 + col] (folds k_hfin).
__global__ __launch_bounds__(256) void k_m2k(
    const unsigned short* __restrict__ A, const unsigned short* __restrict__ Bw,
    const float* __restrict__ bias, float* __restrict__ hd,
    float* __restrict__ out, int last) {
  const int nt = blockIdx.x, mt = blockIdx.y;
  const int tid = threadIdx.x, lane = tid & 63, w = tid >> 6;
  const int l15 = lane & 15, lhi = lane >> 4;
  __shared__ __align__(128) char lds[49152];  // buf b @ b*24576: A 8KB, B 16KB
  const unsigned short* aSrc = A  + (size_t)(mt*32)*1024;
  const unsigned short* bSrc = Bw + (size_t)(nt*64)*1024;

  u16x8 rg[6];
#pragma unroll
  for (int p = 0; p < 6; p++) {
    const int u = tid + p*256;
    const int isB = (u >= 512);
    const int v = isB ? (u - 512) : u;
    const int row = v >> 4, slot = v & 15;
    u16x8 val = *(const u16x8*)((isB ? bSrc : aSrc) + (size_t)row*1024 + slot*8);
    *(u16x8*)(lds + isB*8192 + SWZP(row*256 + slot*16, row)) = val;
  }
#pragma unroll
  for (int p = 0; p < 6; p++) {
    const int u = tid + p*256;
    const int isB = (u >= 512);
    const int v = isB ? (u - 512) : u;
    const int row = v >> 4, slot = v & 15;
    rg[p] = *(const u16x8*)((isB ? bSrc : aSrc) + (size_t)row*1024 + 128 + slot*8);
  }
  __syncthreads();

  f32x4 acc[2][4] = {};
  for (int c = 0; c < 8; c++) {
    const int cur = (c & 1) * 24576;
    const int nxt = 24576 - cur;
    if (c < 7) {
#pragma unroll
      for (int p = 0; p < 6; p++) {
        const int u = tid + p*256;
        const int isB = (u >= 512);
        const int v = isB ? (u - 512) : u;
        const int row = v >> 4, slot = v & 15;
        *(u16x8*)(lds + nxt + isB*8192 + SWZP(row*256 + slot*16, row)) = rg[p];
      }
    }
    if (c < 6) {
#pragma unroll
      for (int p = 0; p < 6; p++) {
        const int u = tid + p*256;
        const int isB = (u >= 512);
        const int v = isB ? (u - 512) : u;
        const int row = v >> 4, slot = v & 15;
        rg[p] = *(const u16x8*)((isB ? bSrc : aSrc) + (size_t)row*1024 +
                                (c+2)*128 + slot*8);
      }
    }
    bf16x8 af[2], bf[4];
#pragma unroll
    for (int mf = 0; mf < 2; mf++) {
      const int row = mf*16 + l15;
      af[mf] = *(const bf16x8*)(lds + cur + SWZP(row*256 + w*64 + lhi*16, row));
    }
#pragma unroll
    for (int nf = 0; nf < 4; nf++) {
      const int row = nf*16 + l15;
      bf[nf] = *(const bf16x8*)(lds + cur + 8192 +
                                SWZP(row*256 + w*64 + lhi*16, row));
    }
#pragma unroll
    for (int mf = 0; mf < 2; mf++)
#pragma unroll
      for (int nf = 0; nf < 4; nf++)
        acc[mf][nf] = __builtin_amdgcn_mfma_f32_16x16x32_bf16(
            af[mf], bf[nf], acc[mf][nf], 0, 0, 0);
    __syncthreads();
  }

#pragma unroll
  for (int mf = 0; mf < 2; mf++)
#pragma unroll
    for (int nf = 0; nf < 4; nf++)
      *(f32x4*)(lds + w*8192 + (mf*4 + nf)*1024 + lane*16) = acc[mf][nf];
  __syncthreads();
#pragma unroll
  for (int pi = 0; pi < 2; pi++) {
    const int p = w*2 + pi;
    f32x4 s = *(const f32x4*)(lds + p*1024 + lane*16);
#pragma unroll
    for (int wv = 1; wv < 4; wv++) {
      f32x4 q = *(const f32x4*)(lds + wv*8192 + p*1024 + lane*16);
      s[0] += q[0]; s[1] += q[1]; s[2] += q[2]; s[3] += q[3];
    }
    const int col = nt*64 + (p & 3)*16 + l15;
    const float bv = bias[col];
#pragma unroll
    for (int r = 0; r < 4; r++) {
      const int row = mt*32 + (p >> 2)*16 + lhi*4 + r;
      float v = fmaxf(s[r] + bv, 0.f);
      hd[(size_t)row*128 + col] = v;
      if (last) out[24576 + (size_t)row*128 + col] = v;
    }
  }
}

extern "C" void kernel_launch(void* const* d_in, const int* in_sizes, int n_in,
                              void* d_out, int out_size, void* d_ws, size_t ws_size,
                              hipStream_t stream) {
  const float* last_pos = (const float*)d_in[0];
  const float* lpr      = (const float*)d_in[1];
  const float* dh       = (const float*)d_in[2];
  const float* dc       = (const float*)d_in[3];
  const float* W_emb = (const float*)d_in[5];
  const float* b_emb = (const float*)d_in[6];
  const float* W_ih  = (const float*)d_in[7];
  const float* b_ih  = (const float*)d_in[8];
  const float* W_hh  = (const float*)d_in[9];
  const float* b_hh  = (const float*)d_in[10];
  const float* W_h2p = (const float*)d_in[11];
  const float* b_h2p = (const float*)d_in[12];
  const float* W_sp  = (const float*)d_in[13];
  const float* b_sp  = (const float*)d_in[14];
  const float* W_pp1 = (const float*)d_in[15];
  const float* b_pp1 = (const float*)d_in[16];
  const float* W_pp2 = (const float*)d_in[17];
  const float* b_pp2 = (const float*)d_in[18];
  const float* W_m1  = (const float*)d_in[19];
  const float* b_m1  = (const float*)d_in[20];
  const float* W_m2  = (const float*)d_in[21];
  const float* b_m2  = (const float*)d_in[22];

  float* ws    = (float*)d_ws;
  float* lp    = ws + OFF_LP;
  float* din   = ws + OFF_DIN;
  float* cst   = ws + OFF_C;
  float* h_dec = ws + OFF_HDEC;
  float* Wc    = ws + OFF_WC;
  float* bc    = ws + OFF_BC;
  float* PW    = ws + OFF_PW;
  float* Aa    = ws + OFF_AA;
  unsigned short* Wp2t  = (unsigned short*)(ws + OFF_WP2T);
  unsigned short* Wm1t  = (unsigned short*)(ws + OFF_WM1T);
  unsigned short* hcatB = (unsigned short*)(ws + OFF_HCATB);
  unsigned short* Wm2tB = (unsigned short*)(ws + OFF_WM2TB);
  unsigned short* midB  = (unsigned short*)(ws + OFF_MIDB);
  float* Wiht  = ws + OFF_WIHT;
  float* Whht  = ws + OFF_WHHT;
  unsigned short* Wfrag = (unsigned short*)(ws + OFF_WFRAG);
  float* out   = (float*)d_out;

  k_setup<<<512, 256, 0, stream>>>(last_pos, lpr, dh, dc, W_emb, b_emb, lp, din, h_dec, cst);
  k_wc<<<2, 256, 0, stream>>>(W_sp, b_sp, W_pp1, b_pp1, Wc, bc);
  { dim3 gt(32, 16); k_tcvt<<<gt, 256, 0, stream>>>(W_pp2, Wp2t, 512, 1024); }
  { dim3 gt(32, 36); k_tcvt<<<gt, 256, 0, stream>>>(W_m1, Wm1t, 1152, 1024); }
  { dim3 gt(4, 32);  k_tcvt<<<gt, 256, 0, stream>>>(W_m2, Wm2tB, 1024, 128); }
  { dim3 gt(2, 16);  k_t32<<<gt, 256, 0, stream>>>(W_ih, Wiht, 512, 64); }
  { dim3 gt(4, 16);  k_t32<<<gt, 256, 0, stream>>>(W_hh, Whht, 512, 128); }
  k_frag<<<256, 256, 0, stream>>>(Wp2t, Wfrag);

  for (int t = 0; t < T_SEQ; t++) {
    k_step1<<<256, 512, 0, stream>>>(din, h_dec, cst, hcatB, lp, out,
                                     Wiht, b_ih, Whht, b_hh, W_h2p, b_h2p,
                                     W_emb, b_emb, W_pp1 + 64*512, Wc, bc,
                                     PW, Aa, t);
    k_pool10<<<256, 512, 0, stream>>>(Aa, PW, Wfrag, b_pp2, hcatB);
    { dim3 gm(16, 16); k_m1k<<<gm, 256, 0, stream>>>(hcatB, Wm1t, b_m1, midB); }
    { dim3 gm(2, 32);  k_m2k<<<gm, 256, 0, stream>>>(midB, Wm2tB, b_m2, h_dec,
                                                     out, t == T_SEQ-1); }
  }
}

// Round 17
// 1048.307 us; speedup vs baseline: 1.5151x; 1.5151x over previous
//
#include <hip/hip_runtime.h>
#include <math.h>

#define T_SEQ 12
// B=1024, NG=32, G=32, E=64, H=128, PP=512, BOT=1024, MLPD=1024

typedef __bf16 bf16x8 __attribute__((ext_vector_type(8)));
typedef float f32x4 __attribute__((ext_vector_type(4)));
typedef unsigned short u16x8 __attribute__((ext_vector_type(8)));

static __device__ __forceinline__ unsigned short bf16bits(float x) {
  return __builtin_bit_cast(unsigned short, (__bf16)x);
}

// Workspace layout (float offsets)
enum : int {
  OFF_LP    = 0,        // [1024,2]
  OFF_DIN   = 2048,     // [1024,64]
  OFF_C     = 198656,   // [1024,128]
  OFF_HDEC  = 329728,   // [1024,128]
  OFF_WC    = 460800,   // [2,512]
  OFF_BC    = 461824,   // [512]
  OFF_PW    = 462336,   // [1024,512]
  OFF_AA    = 986624,   // [1024,512]
  OFF_WP2T  = 1510912,  // [1024,512] bf16
  OFF_WM1T  = 1773056,  // [1024,1152] bf16
  OFF_HCATB = 2362880,  // [1024,1152] bf16 (h | pool)
  OFF_WM2TB = 2952704,  // [128,1024] bf16
  OFF_MIDB  = 3018240,  // [1024,1024] bf16
  OFF_WIHT  = 3542528,  // [64,512] f32 (W_ih^T)
  OFF_WHHT  = 3575296,  // [128,512] f32 (W_hh^T)
  OFF_WFRAG = 3640832   // [1024 frags][64 lanes][8] bf16 = 131072 floats
};                      // end 3771904 floats = 15.1 MB

// XOR swizzle: permute 16B slots within each 128B group by row&7
#define SWZP(byte, row) ((byte) ^ (((row) & 7) << 4))

__global__ __launch_bounds__(256) void k_setup(
    const float* __restrict__ last_pos, const float* __restrict__ lpr,
    const float* __restrict__ dh, const float* __restrict__ dc,
    const float* __restrict__ W_emb, const float* __restrict__ b_emb,
    float* __restrict__ lp, float* __restrict__ din,
    float* __restrict__ h_dec, float* __restrict__ c) {
  int idx = blockIdx.x * 256 + threadIdx.x;  // 0..131071
  if (idx < 2048) lp[idx] = last_pos[idx];
  h_dec[idx] = dh[idx];
  c[idx] = dc[idx];
  if (idx < 65536) {
    int b = idx >> 6, e = idx & 63;
    din[idx] = lpr[b*2] * W_emb[e] + lpr[b*2+1] * W_emb[64+e] + b_emb[e];
  }
}

__global__ __launch_bounds__(256) void k_wc(
    const float* __restrict__ W_sp, const float* __restrict__ b_sp,
    const float* __restrict__ W_pp1, const float* __restrict__ b_pp1,
    float* __restrict__ Wc, float* __restrict__ bc) {
  int n = blockIdx.x * 256 + threadIdx.x;
  if (n >= 512) return;
  float a0 = 0.f, a1 = 0.f, ab = 0.f;
#pragma unroll 8
  for (int k = 0; k < 64; k++) {
    float w = W_pp1[k*512 + n];
    a0 += W_sp[k] * w;
    a1 += W_sp[64+k] * w;
    ab += b_sp[k] * w;
  }
  Wc[n] = a0; Wc[512+n] = a1; bc[n] = ab + b_pp1[n];
}

// Transpose + convert fp32 [R][C] -> bf16 [C][R]
__global__ __launch_bounds__(256) void k_tcvt(
    const float* __restrict__ src, unsigned short* __restrict__ dst,
    int R, int C) {
  __shared__ float t[32][33];
  const int bx = blockIdx.x * 32, by = blockIdx.y * 32;
  const int tx = threadIdx.x & 31, ty = threadIdx.x >> 5;
#pragma unroll
  for (int i = 0; i < 32; i += 8) t[ty+i][tx] = src[(size_t)(by+ty+i)*C + bx+tx];
  __syncthreads();
#pragma unroll
  for (int i = 0; i < 32; i += 8)
    dst[(size_t)(bx+ty+i)*R + by+tx] = bf16bits(t[tx][ty+i]);
}

// Transpose fp32 [R][C] -> fp32 [C][R]
__global__ __launch_bounds__(256) void k_t32(
    const float* __restrict__ src, float* __restrict__ dst, int R, int C) {
  __shared__ float t[32][33];
  const int bx = blockIdx.x * 32, by = blockIdx.y * 32;
  const int tx = threadIdx.x & 31, ty = threadIdx.x >> 5;
#pragma unroll
  for (int i = 0; i < 32; i += 8) t[ty+i][tx] = src[(size_t)(by+ty+i)*C + bx+tx];
  __syncthreads();
#pragma unroll
  for (int i = 0; i < 32; i += 8)
    dst[(size_t)(bx+ty+i)*R + by+tx] = t[tx][ty+i];
}

// Re-arrange Wp2t [1024n][512k] into MFMA B-fragment order:
// Wfrag[fid][lane][8], fid = nbb*16 + kstep.
__global__ __launch_bounds__(256) void k_frag(
    const unsigned short* __restrict__ Wp2t, unsigned short* __restrict__ Wfrag) {
  const int tid = blockIdx.x * 256 + threadIdx.x;  // 0..65535
  const int fid = tid >> 6, l = tid & 63;
  const int nbb = fid >> 4, ks = fid & 15;
  u16x8 v = *(const u16x8*)(Wp2t + (size_t)(nbb*16 + (l & 15))*512 +
                            ks*32 + (l >> 4)*8);
  *(u16x8*)(Wfrag + (size_t)tid*8) = v;
}

// Fused LSTM + h2pos + pool-A-prep: 4 batch rows/block, 512 threads, 256 blocks.
__global__ __launch_bounds__(512) void k_step1(
    float* __restrict__ din, const float* __restrict__ h_dec,
    float* __restrict__ cst, unsigned short* __restrict__ hcatB,
    float* __restrict__ lp, float* __restrict__ pred,
    const float* __restrict__ Wiht, const float* __restrict__ b_ih,
    const float* __restrict__ Whht, const float* __restrict__ b_hh,
    const float* __restrict__ W_h2p, const float* __restrict__ b_h2p,
    const float* __restrict__ W_emb, const float* __restrict__ b_emb,
    const float* __restrict__ W1b, const float* __restrict__ Wc,
    const float* __restrict__ bc,
    float* __restrict__ PW, float* __restrict__ Aa, int t) {
  const int b0 = blockIdx.x * 4;
  const int tid = threadIdx.x;
  __shared__ float xh[4*192];
  __shared__ float gl[4*512];
  __shared__ float hbuf[4*128];
  __shared__ float relS[8], curS[8];

  for (int i = tid; i < 768; i += 512) {
    int r = i / 192, k = i - r*192;
    xh[i] = (k < 64) ? din[(b0+r)*64 + k] : h_dec[(b0+r)*128 + k - 64];
  }
  __syncthreads();
  {
    const int n = tid;
    float bias = b_ih[n] + b_hh[n];
    float acc[4] = {bias, bias, bias, bias};
#pragma unroll 8
    for (int k = 0; k < 64; k++) {
      float wv = Wiht[k*512 + n];
#pragma unroll
      for (int r = 0; r < 4; r++) acc[r] += xh[r*192 + k] * wv;
    }
#pragma unroll 8
    for (int k = 0; k < 128; k++) {
      float wv = Whht[k*512 + n];
#pragma unroll
      for (int r = 0; r < 4; r++) acc[r] += xh[r*192 + 64 + k] * wv;
    }
#pragma unroll
    for (int r = 0; r < 4; r++) gl[r*512 + n] = acc[r];
  }
  __syncthreads();
  {
    int r = tid >> 7, hh = tid & 127;
    float ig = gl[r*512 + hh],       fg = gl[r*512 + 128 + hh];
    float gg = gl[r*512 + 256 + hh], og = gl[r*512 + 384 + hh];
    ig = 1.f/(1.f+expf(-ig)); fg = 1.f/(1.f+expf(-fg));
    gg = tanhf(gg);           og = 1.f/(1.f+expf(-og));
    int row = b0 + r;
    float c2 = fg * cst[row*128 + hh] + ig * gg;
    float h2 = og * tanhf(c2);
    cst[row*128 + hh] = c2;
    hbuf[r*128 + hh] = h2;
    hcatB[(size_t)row*1152 + hh] = bf16bits(h2);
  }
  __syncthreads();
  if (tid < 128) {
    int r = tid >> 5, col = (tid >> 4) & 1, l16 = tid & 15;
    float s = 0.f;
    for (int k = l16; k < 128; k += 16) s += hbuf[r*128 + k] * W_h2p[k*2 + col];
#pragma unroll
    for (int off = 8; off > 0; off >>= 1) s += __shfl_xor(s, off);
    if (l16 == 0) {
      float rel = s + b_h2p[col];
      float old = lp[(b0+r)*2 + col];
      relS[r*2 + col] = rel;
      curS[r*2 + col] = old + rel;
      lp[(b0+r)*2 + col] = old + rel;
      pred[t*2048 + (b0+r)*2 + col] = rel;
    }
  }
  __syncthreads();
  if (tid < 256) {
    int r = tid >> 6, e = tid & 63;
    din[(b0+r)*64 + e] = relS[r*2]*W_emb[e] + relS[r*2+1]*W_emb[64+e] + b_emb[e];
  }
  {
    const int n = tid;
    float acc[4] = {0.f, 0.f, 0.f, 0.f};
#pragma unroll 4
    for (int k = 0; k < 128; k++) {
      float wv = W1b[k*512 + n];
#pragma unroll
      for (int r = 0; r < 4; r++) acc[r] += hbuf[r*128 + k] * wv;
    }
    float wc0 = Wc[n], wc1 = Wc[512+n], bcv = bc[n];
#pragma unroll
    for (int r = 0; r < 4; r++) {
      float pw = curS[r*2]*wc0 + curS[r*2+1]*wc1;
      PW[(size_t)(b0+r)*512 + n] = pw;
      Aa[(size_t)(b0+r)*512 + n] = acc[r] + pw + bcv;
    }
  }
}

// --- Pool GEMM v11: 2 BLOCKS PER CU. A-tile 64 rows (2 i-values, 64KB) +
// single 16KB B chunk in MFMA-fragment layout = 80KB LDS exactly.
// Grid 512 = (mt 0..15, g 0..31), 256 thr (4 waves, 1m x 4n).
// 2 barriers/k-step, but co-resident blocks' stalls interleave (m114).
__global__ __launch_bounds__(256) void k_pool11(
    const float* __restrict__ Aa, const float* __restrict__ PW,
    const unsigned short* __restrict__ Wfrag, const float* __restrict__ bp2,
    unsigned short* __restrict__ hcatB) {
  const int bid = blockIdx.x;                   // 0..511
  const int mt = (bid >> 3) & 15;               // XCD = bid&7
  const int g  = (bid & 7) + ((bid >> 7) << 3); // bijective, 4 g per XCD slice
  const int tid = threadIdx.x, lane = tid & 63, w = tid >> 6;  // 4 waves
  const int l15 = lane & 15, lhi = lane >> 4;
  __shared__ __align__(128) char lds[81920];
  char* As = lds;            // [64 rows][1024B] swizzled
  char* Bs = lds + 65536;    // [16 nb][1024B] fragment-layout chunk

  // Build A tile: rows r = ii*32 + j (ii = 0,1; i = mt*2 + ii).
  {
#pragma unroll 4
    for (int rr = 0; rr < 16; rr++) {
      const int r = rr * 4 + w;
      const int j = r & 31, ii = r >> 5;
      const float* aRow = Aa + (size_t)(g*32 + j)*512 + lane*8;
      const float* pRow = PW + (size_t)(g*32 + mt*2 + ii)*512 + lane*8;
      float4 a0 = *(const float4*)aRow;
      float4 a1 = *(const float4*)(aRow + 4);
      float4 p0 = *(const float4*)pRow;
      float4 p1 = *(const float4*)(pRow + 4);
      bf16x8 y;
      y[0] = (__bf16)fmaxf(a0.x - p0.x, 0.f);
      y[1] = (__bf16)fmaxf(a0.y - p0.y, 0.f);
      y[2] = (__bf16)fmaxf(a0.z - p0.z, 0.f);
      y[3] = (__bf16)fmaxf(a0.w - p0.w, 0.f);
      y[4] = (__bf16)fmaxf(a1.x - p1.x, 0.f);
      y[5] = (__bf16)fmaxf(a1.y - p1.y, 0.f);
      y[6] = (__bf16)fmaxf(a1.z - p1.z, 0.f);
      y[7] = (__bf16)fmaxf(a1.w - p1.w, 0.f);
      *(bf16x8*)(As + SWZP(r*1024 + lane*16, r)) = y;
    }
  }

  // B staging: 16KB chunk = 1024 16B-units; thread owns 4 (u = tid + p*256).
  // unit u: nb = u>>6, lane-slot = u&63; gfo = nb*8192 + slot*8 (shorts).
  size_t gfo[4];
#pragma unroll
  for (int p = 0; p < 4; p++) {
    const int u = tid + p*256;
    gfo[p] = (size_t)(u >> 6) * 8192 + (size_t)(u & 63) * 8;
  }

  // prologue: stage chunk 0 directly; load chunk 1 -> regs
  u16x8 rr_[4];
#pragma unroll
  for (int p = 0; p < 4; p++) {
    u16x8 s = *(const u16x8*)(Wfrag + gfo[p]);
    *(u16x8*)(Bs + (tid + p*256)*16) = s;
  }
#pragma unroll
  for (int p = 0; p < 4; p++)
    rr_[p] = *(const u16x8*)(Wfrag + (size_t)512 + gfo[p]);  // q=1 base
  __syncthreads();

  for (int nt = 0; nt < 4; nt++) {
    f32x4 acc[4][4] = {};
    for (int k0 = 0; k0 < 16; k0++) {
      const int q = nt*16 + k0;
      // reads: B frags (this step's chunk) + A frags
      bf16x8 bfr[4], af[4];
#pragma unroll
      for (int nf = 0; nf < 4; nf++)
        bfr[nf] = *(const bf16x8*)(Bs + (w*4 + nf)*1024 + lane*16);
#pragma unroll
      for (int mf = 0; mf < 4; mf++) {
        const int row = mf*16 + l15;
        af[mf] = *(const bf16x8*)(As + SWZP(row*1024 + k0*64 + lhi*16, row));
      }
      __syncthreads();   // all reads of chunk q complete
      // write chunk q+1 (regs loaded at q-1 / prologue)
      if (q < 63) {
#pragma unroll
        for (int p = 0; p < 4; p++)
          *(u16x8*)(Bs + (tid + p*256)*16) = rr_[p];
      }
      // issue loads for chunk q+2
      if (q < 62) {
        const int q2 = q + 2;
        const size_t base = (size_t)((q2 >> 4) * 256 + (q2 & 15)) * 512;
#pragma unroll
        for (int p = 0; p < 4; p++)
          rr_[p] = *(const u16x8*)(Wfrag + base + gfo[p]);
      }
      // MFMA (register operands; overlaps the writes)
#pragma unroll
      for (int mf = 0; mf < 4; mf++)
#pragma unroll
        for (int nf = 0; nf < 4; nf++)
          acc[mf][nf] = __builtin_amdgcn_mfma_f32_16x16x32_bf16(
              af[mf], bfr[nf], acc[mf][nf], 0, 0, 0);
      __syncthreads();   // chunk q+1 writes visible
    }
    // epilogue: max over j (mf pairs), bias, relu -> hcatB pool columns
#pragma unroll
    for (int isub = 0; isub < 2; isub++)
#pragma unroll
      for (int nf = 0; nf < 4; nf++) {
        f32x4 v0 = acc[isub*2][nf], v1 = acc[isub*2 + 1][nf];
        float mx = fmaxf(fmaxf(fmaxf(v0[0], v0[1]), fmaxf(v0[2], v0[3])),
                         fmaxf(fmaxf(v1[0], v1[1]), fmaxf(v1[2], v1[3])));
        mx = fmaxf(mx, __shfl_xor(mx, 16));
        mx = fmaxf(mx, __shfl_xor(mx, 32));
        if (lane < 16) {
          const int n = nt*256 + w*64 + nf*16 + lane;
          const int i = mt*2 + isub;
          hcatB[(size_t)(g*32 + i)*1152 + 128 + n] =
              bf16bits(fmaxf(mx + bp2[n], 0.f));
        }
      }
  }
}

// mid = relu(hcatB @ Wm1t^T + b_m1) -> bf16 midB.
// K-split-wave GEMM (R11): grid (16,16), 256 thr, 4 waves k-split.
__global__ __launch_bounds__(256) void k_m1k(
    const unsigned short* __restrict__ A, const unsigned short* __restrict__ Bw,
    const float* __restrict__ bias, unsigned short* __restrict__ outB) {
  const int nt = blockIdx.x, mt = blockIdx.y;
  const int tid = threadIdx.x, lane = tid & 63, w = tid >> 6;
  const int l15 = lane & 15, lhi = lane >> 4;
  __shared__ __align__(128) char lds[65536];  // buf b: A @ b*32768, B @ +16384
  const unsigned short* aSrc = A  + (size_t)(mt*64)*1152;
  const unsigned short* bSrc = Bw + (size_t)(nt*64)*1152;

  u16x8 rg[8];
#pragma unroll
  for (int p = 0; p < 8; p++) {
    const int u = tid + p*256;
    const int isB = u >> 10, v = u & 1023;
    const int row = v >> 4, slot = v & 15;
    u16x8 val = *(const u16x8*)((isB ? bSrc : aSrc) + (size_t)row*1152 + slot*8);
    *(u16x8*)(lds + isB*16384 + SWZP(row*256 + slot*16, row)) = val;
  }
#pragma unroll
  for (int p = 0; p < 8; p++) {
    const int u = tid + p*256;
    const int isB = u >> 10, v = u & 1023;
    const int row = v >> 4, slot = v & 15;
    rg[p] = *(const u16x8*)((isB ? bSrc : aSrc) + (size_t)row*1152 + 128 + slot*8);
  }
  __syncthreads();

  f32x4 acc[4][4] = {};
  for (int c = 0; c < 9; c++) {
    const int cur = (c & 1) * 32768;
    const int nxt = 32768 - cur;
    if (c < 8) {
#pragma unroll
      for (int p = 0; p < 8; p++) {
        const int u = tid + p*256;
        const int isB = u >> 10, v = u & 1023;
        const int row = v >> 4, slot = v & 15;
        *(u16x8*)(lds + nxt + isB*16384 + SWZP(row*256 + slot*16, row)) = rg[p];
      }
    }
    if (c < 7) {
#pragma unroll
      for (int p = 0; p < 8; p++) {
        const int u = tid + p*256;
        const int isB = u >> 10, v = u & 1023;
        const int row = v >> 4, slot = v & 15;
        rg[p] = *(const u16x8*)((isB ? bSrc : aSrc) + (size_t)row*1152 +
                                (c+2)*128 + slot*8);
      }
    }
    bf16x8 af[4], bf[4];
#pragma unroll
    for (int mf = 0; mf < 4; mf++) {
      const int row = mf*16 + l15;
      af[mf] = *(const bf16x8*)(lds + cur + SWZP(row*256 + w*64 + lhi*16, row));
    }
#pragma unroll
    for (int nf = 0; nf < 4; nf++) {
      const int row = nf*16 + l15;
      bf[nf] = *(const bf16x8*)(lds + cur + 16384 +
                                SWZP(row*256 + w*64 + lhi*16, row));
    }
#pragma unroll
    for (int mf = 0; mf < 4; mf++)
#pragma unroll
      for (int nf = 0; nf < 4; nf++)
        acc[mf][nf] = __builtin_amdgcn_mfma_f32_16x16x32_bf16(
            af[mf], bf[nf], acc[mf][nf], 0, 0, 0);
    __syncthreads();
  }

#pragma unroll
  for (int mf = 0; mf < 4; mf++)
#pragma unroll
    for (int nf = 0; nf < 4; nf++)
      *(f32x4*)(lds + w*16384 + (mf*4 + nf)*1024 + lane*16) = acc[mf][nf];
  __syncthreads();
#pragma unroll
  for (int pi = 0; pi < 4; pi++) {
    const int p = w*4 + pi;
    f32x4 s = *(const f32x4*)(lds + p*1024 + lane*16);
#pragma unroll
    for (int wv = 1; wv < 4; wv++) {
      f32x4 q = *(const f32x4*)(lds + wv*16384 + p*1024 + lane*16);
      s[0] += q[0]; s[1] += q[1]; s[2] += q[2]; s[3] += q[3];
    }
    const int col = nt*64 + (p & 3)*16 + l15;
    const float bv = bias[col];
#pragma unroll
    for (int r = 0; r < 4; r++) {
      const int row = mt*64 + (p >> 2)*16 + lhi*4 + r;
      outB[(size_t)row*1024 + col] = bf16bits(fmaxf(s[r] + bv, 0.f));
    }
  }
}

// h_dec = relu(midB @ Wm2tB^T + b_m2) fp32. K-split-wave (R11).
// At t==T_SEQ-1 also writes out (folds k_hfin).
__global__ __launch_bounds__(256) void k_m2k(
    const unsigned short* __restrict__ A, const unsigned short* __restrict__ Bw,
    const float* __restrict__ bias, float* __restrict__ hd,
    float* __restrict__ out, int last) {
  const int nt = blockIdx.x, mt = blockIdx.y;
  const int tid = threadIdx.x, lane = tid & 63, w = tid >> 6;
  const int l15 = lane & 15, lhi = lane >> 4;
  __shared__ __align__(128) char lds[49152];  // buf b @ b*24576: A 8KB, B 16KB
  const unsigned short* aSrc = A  + (size_t)(mt*32)*1024;
  const unsigned short* bSrc = Bw + (size_t)(nt*64)*1024;

  u16x8 rg[6];
#pragma unroll
  for (int p = 0; p < 6; p++) {
    const int u = tid + p*256;
    const int isB = (u >= 512);
    const int v = isB ? (u - 512) : u;
    const int row = v >> 4, slot = v & 15;
    u16x8 val = *(const u16x8*)((isB ? bSrc : aSrc) + (size_t)row*1024 + slot*8);
    *(u16x8*)(lds + isB*8192 + SWZP(row*256 + slot*16, row)) = val;
  }
#pragma unroll
  for (int p = 0; p < 6; p++) {
    const int u = tid + p*256;
    const int isB = (u >= 512);
    const int v = isB ? (u - 512) : u;
    const int row = v >> 4, slot = v & 15;
    rg[p] = *(const u16x8*)((isB ? bSrc : aSrc) + (size_t)row*1024 + 128 + slot*8);
  }
  __syncthreads();

  f32x4 acc[2][4] = {};
  for (int c = 0; c < 8; c++) {
    const int cur = (c & 1) * 24576;
    const int nxt = 24576 - cur;
    if (c < 7) {
#pragma unroll
      for (int p = 0; p < 6; p++) {
        const int u = tid + p*256;
        const int isB = (u >= 512);
        const int v = isB ? (u - 512) : u;
        const int row = v >> 4, slot = v & 15;
        *(u16x8*)(lds + nxt + isB*8192 + SWZP(row*256 + slot*16, row)) = rg[p];
      }
    }
    if (c < 6) {
#pragma unroll
      for (int p = 0; p < 6; p++) {
        const int u = tid + p*256;
        const int isB = (u >= 512);
        const int v = isB ? (u - 512) : u;
        const int row = v >> 4, slot = v & 15;
        rg[p] = *(const u16x8*)((isB ? bSrc : aSrc) + (size_t)row*1024 +
                                (c+2)*128 + slot*8);
      }
    }
    bf16x8 af[2], bf[4];
#pragma unroll
    for (int mf = 0; mf < 2; mf++) {
      const int row = mf*16 + l15;
      af[mf] = *(const bf16x8*)(lds + cur + SWZP(row*256 + w*64 + lhi*16, row));
    }
#pragma unroll
    for (int nf = 0; nf < 4; nf++) {
      const int row = nf*16 + l15;
      bf[nf] = *(const bf16x8*)(lds + cur + 8192 +
                                SWZP(row*256 + w*64 + lhi*16, row));
    }
#pragma unroll
    for (int mf = 0; mf < 2; mf++)
#pragma unroll
      for (int nf = 0; nf < 4; nf++)
        acc[mf][nf] = __builtin_amdgcn_mfma_f32_16x16x32_bf16(
            af[mf], bf[nf], acc[mf][nf], 0, 0, 0);
    __syncthreads();
  }

#pragma unroll
  for (int mf = 0; mf < 2; mf++)
#pragma unroll
    for (int nf = 0; nf < 4; nf++)
      *(f32x4*)(lds + w*8192 + (mf*4 + nf)*1024 + lane*16) = acc[mf][nf];
  __syncthreads();
#pragma unroll
  for (int pi = 0; pi < 2; pi++) {
    const int p = w*2 + pi;
    f32x4 s = *(const f32x4*)(lds + p*1024 + lane*16);
#pragma unroll
    for (int wv = 1; wv < 4; wv++) {
      f32x4 q = *(const f32x4*)(lds + wv*8192 + p*1024 + lane*16);
      s[0] += q[0]; s[1] += q[1]; s[2] += q[2]; s[3] += q[3];
    }
    const int col = nt*64 + (p & 3)*16 + l15;
    const float bv = bias[col];
#pragma unroll
    for (int r = 0; r < 4; r++) {
      const int row = mt*32 + (p >> 2)*16 + lhi*4 + r;
      float v = fmaxf(s[r] + bv, 0.f);
      hd[(size_t)row*128 + col] = v;
      if (last) out[24576 + (size_t)row*128 + col] = v;
    }
  }
}

extern "C" void kernel_launch(void* const* d_in, const int* in_sizes, int n_in,
                              void* d_out, int out_size, void* d_ws, size_t ws_size,
                              hipStream_t stream) {
  const float* last_pos = (const float*)d_in[0];
  const float* lpr      = (const float*)d_in[1];
  const float* dh       = (const float*)d_in[2];
  const float* dc       = (const float*)d_in[3];
  const float* W_emb = (const float*)d_in[5];
  const float* b_emb = (const float*)d_in[6];
  const float* W_ih  = (const float*)d_in[7];
  const float* b_ih  = (const float*)d_in[8];
  const float* W_hh  = (const float*)d_in[9];
  const float* b_hh  = (const float*)d_in[10];
  const float* W_h2p = (const float*)d_in[11];
  const float* b_h2p = (const float*)d_in[12];
  const float* W_sp  = (const float*)d_in[13];
  const float* b_sp  = (const float*)d_in[14];
  const float* W_pp1 = (const float*)d_in[15];
  const float* b_pp1 = (const float*)d_in[16];
  const float* W_pp2 = (const float*)d_in[17];
  const float* b_pp2 = (const float*)d_in[18];
  const float* W_m1  = (const float*)d_in[19];
  const float* b_m1  = (const float*)d_in[20];
  const float* W_m2  = (const float*)d_in[21];
  const float* b_m2  = (const float*)d_in[22];

  float* ws    = (float*)d_ws;
  float* lp    = ws + OFF_LP;
  float* din   = ws + OFF_DIN;
  float* cst   = ws + OFF_C;
  float* h_dec = ws + OFF_HDEC;
  float* Wc    = ws + OFF_WC;
  float* bc    = ws + OFF_BC;
  float* PW    = ws + OFF_PW;
  float* Aa    = ws + OFF_AA;
  unsigned short* Wp2t  = (unsigned short*)(ws + OFF_WP2T);
  unsigned short* Wm1t  = (unsigned short*)(ws + OFF_WM1T);
  unsigned short* hcatB = (unsigned short*)(ws + OFF_HCATB);
  unsigned short* Wm2tB = (unsigned short*)(ws + OFF_WM2TB);
  unsigned short* midB  = (unsigned short*)(ws + OFF_MIDB);
  float* Wiht  = ws + OFF_WIHT;
  float* Whht  = ws + OFF_WHHT;
  unsigned short* Wfrag = (unsigned short*)(ws + OFF_WFRAG);
  float* out   = (float*)d_out;

  k_setup<<<512, 256, 0, stream>>>(last_pos, lpr, dh, dc, W_emb, b_emb, lp, din, h_dec, cst);
  k_wc<<<2, 256, 0, stream>>>(W_sp, b_sp, W_pp1, b_pp1, Wc, bc);
  { dim3 gt(32, 16); k_tcvt<<<gt, 256, 0, stream>>>(W_pp2, Wp2t, 512, 1024); }
  { dim3 gt(32, 36); k_tcvt<<<gt, 256, 0, stream>>>(W_m1, Wm1t, 1152, 1024); }
  { dim3 gt(4, 32);  k_tcvt<<<gt, 256, 0, stream>>>(W_m2, Wm2tB, 1024, 128); }
  { dim3 gt(2, 16);  k_t32<<<gt, 256, 0, stream>>>(W_ih, Wiht, 512, 64); }
  { dim3 gt(4, 16);  k_t32<<<gt, 256, 0, stream>>>(W_hh, Whht, 512, 128); }
  k_frag<<<256, 256, 0, stream>>>(Wp2t, Wfrag);

  for (int t = 0; t < T_SEQ; t++) {
    k_step1<<<256, 512, 0, stream>>>(din, h_dec, cst, hcatB, lp, out,
                                     Wiht, b_ih, Whht, b_hh, W_h2p, b_h2p,
                                     W_emb, b_emb, W_pp1 + 64*512, Wc, bc,
                                     PW, Aa, t);
    k_pool11<<<512, 256, 0, stream>>>(Aa, PW, Wfrag, b_pp2, hcatB);
    { dim3 gm(16, 16); k_m1k<<<gm, 256, 0, stream>>>(hcatB, Wm1t, b_m1, midB); }
    { dim3 gm(2, 32);  k_m2k<<<gm, 256, 0, stream>>>(midB, Wm2tB, b_m2, h_dec,
                                                     out, t == T_SEQ-1); }
  }
}

// Round 18
// 962.534 us; speedup vs baseline: 1.6501x; 1.0891x over previous
//
#include <hip/hip_runtime.h>
#include <math.h>

#define T_SEQ 12
// B=1024, NG=32, G=32, E=64, H=128, PP=512, BOT=1024, MLPD=1024

typedef __bf16 bf16x8 __attribute__((ext_vector_type(8)));
typedef float f32x4 __attribute__((ext_vector_type(4)));
typedef unsigned short u16x8 __attribute__((ext_vector_type(8)));

static __device__ __forceinline__ unsigned short bf16bits(float x) {
  return __builtin_bit_cast(unsigned short, (__bf16)x);
}

// Workspace layout (float offsets)
enum : int {
  OFF_LP    = 0,        // [1024,2]
  OFF_DIN   = 2048,     // [1024,64]
  OFF_C     = 198656,   // [1024,128]
  OFF_HDEC  = 329728,   // [1024,128]
  OFF_WC    = 460800,   // [2,512]
  OFF_BC    = 461824,   // [512]
  OFF_PW    = 462336,   // [1024,512]
  OFF_AA    = 986624,   // [1024,512]
  OFF_WP2T  = 1510912,  // [1024,512] bf16
  OFF_WM1T  = 1773056,  // [1024,1152] bf16
  OFF_HCATB = 2362880,  // [1024,1152] bf16 (h | pool)
  OFF_WM2TB = 2952704,  // [128,1024] bf16
  OFF_MIDB  = 3018240,  // [1024,1024] bf16
  OFF_WIHT  = 3542528,  // [64,512] f32 (W_ih^T)
  OFF_WHHT  = 3575296,  // [128,512] f32 (W_hh^T)
  OFF_WFRAG = 3640832   // [1024 frags][64 lanes][8] bf16 = 131072 floats
};                      // end 3771904 floats = 15.1 MB

// XOR swizzle: permute 16B slots within each 128B group by row&7
#define SWZP(byte, row) ((byte) ^ (((row) & 7) << 4))

__global__ __launch_bounds__(256) void k_setup(
    const float* __restrict__ last_pos, const float* __restrict__ lpr,
    const float* __restrict__ dh, const float* __restrict__ dc,
    const float* __restrict__ W_emb, const float* __restrict__ b_emb,
    float* __restrict__ lp, float* __restrict__ din,
    float* __restrict__ h_dec, float* __restrict__ c) {
  int idx = blockIdx.x * 256 + threadIdx.x;  // 0..131071
  if (idx < 2048) lp[idx] = last_pos[idx];
  h_dec[idx] = dh[idx];
  c[idx] = dc[idx];
  if (idx < 65536) {
    int b = idx >> 6, e = idx & 63;
    din[idx] = lpr[b*2] * W_emb[e] + lpr[b*2+1] * W_emb[64+e] + b_emb[e];
  }
}

__global__ __launch_bounds__(256) void k_wc(
    const float* __restrict__ W_sp, const float* __restrict__ b_sp,
    const float* __restrict__ W_pp1, const float* __restrict__ b_pp1,
    float* __restrict__ Wc, float* __restrict__ bc) {
  int n = blockIdx.x * 256 + threadIdx.x;
  if (n >= 512) return;
  float a0 = 0.f, a1 = 0.f, ab = 0.f;
#pragma unroll 8
  for (int k = 0; k < 64; k++) {
    float w = W_pp1[k*512 + n];
    a0 += W_sp[k] * w;
    a1 += W_sp[64+k] * w;
    ab += b_sp[k] * w;
  }
  Wc[n] = a0; Wc[512+n] = a1; bc[n] = ab + b_pp1[n];
}

// Transpose + convert fp32 [R][C] -> bf16 [C][R]
__global__ __launch_bounds__(256) void k_tcvt(
    const float* __restrict__ src, unsigned short* __restrict__ dst,
    int R, int C) {
  __shared__ float t[32][33];
  const int bx = blockIdx.x * 32, by = blockIdx.y * 32;
  const int tx = threadIdx.x & 31, ty = threadIdx.x >> 5;
#pragma unroll
  for (int i = 0; i < 32; i += 8) t[ty+i][tx] = src[(size_t)(by+ty+i)*C + bx+tx];
  __syncthreads();
#pragma unroll
  for (int i = 0; i < 32; i += 8)
    dst[(size_t)(bx+ty+i)*R + by+tx] = bf16bits(t[tx][ty+i]);
}

// Transpose fp32 [R][C] -> fp32 [C][R]
__global__ __launch_bounds__(256) void k_t32(
    const float* __restrict__ src, float* __restrict__ dst, int R, int C) {
  __shared__ float t[32][33];
  const int bx = blockIdx.x * 32, by = blockIdx.y * 32;
  const int tx = threadIdx.x & 31, ty = threadIdx.x >> 5;
#pragma unroll
  for (int i = 0; i < 32; i += 8) t[ty+i][tx] = src[(size_t)(by+ty+i)*C + bx+tx];
  __syncthreads();
#pragma unroll
  for (int i = 0; i < 32; i += 8)
    dst[(size_t)(bx+ty+i)*R + by+tx] = t[tx][ty+i];
}

// Re-arrange Wp2t [1024n][512k] into MFMA B-fragment order:
// Wfrag[fid][lane][8], fid = nbb*16 + kstep.
__global__ __launch_bounds__(256) void k_frag(
    const unsigned short* __restrict__ Wp2t, unsigned short* __restrict__ Wfrag) {
  const int tid = blockIdx.x * 256 + threadIdx.x;  // 0..65535
  const int fid = tid >> 6, l = tid & 63;
  const int nbb = fid >> 4, ks = fid & 15;
  u16x8 v = *(const u16x8*)(Wp2t + (size_t)(nbb*16 + (l & 15))*512 +
                            ks*32 + (l >> 4)*8);
  *(u16x8*)(Wfrag + (size_t)tid*8) = v;
}

// Fused LSTM + h2pos + pool-A-prep: 4 batch rows/block, 512 threads, 256 blocks.
__global__ __launch_bounds__(512) void k_step1(
    float* __restrict__ din, const float* __restrict__ h_dec,
    float* __restrict__ cst, unsigned short* __restrict__ hcatB,
    float* __restrict__ lp, float* __restrict__ pred,
    const float* __restrict__ Wiht, const float* __restrict__ b_ih,
    const float* __restrict__ Whht, const float* __restrict__ b_hh,
    const float* __restrict__ W_h2p, const float* __restrict__ b_h2p,
    const float* __restrict__ W_emb, const float* __restrict__ b_emb,
    const float* __restrict__ W1b, const float* __restrict__ Wc,
    const float* __restrict__ bc,
    float* __restrict__ PW, float* __restrict__ Aa, int t) {
  const int b0 = blockIdx.x * 4;
  const int tid = threadIdx.x;
  __shared__ float xh[4*192];
  __shared__ float gl[4*512];
  __shared__ float hbuf[4*128];
  __shared__ float relS[8], curS[8];

  for (int i = tid; i < 768; i += 512) {
    int r = i / 192, k = i - r*192;
    xh[i] = (k < 64) ? din[(b0+r)*64 + k] : h_dec[(b0+r)*128 + k - 64];
  }
  __syncthreads();
  {
    const int n = tid;
    float bias = b_ih[n] + b_hh[n];
    float acc[4] = {bias, bias, bias, bias};
#pragma unroll 8
    for (int k = 0; k < 64; k++) {
      float wv = Wiht[k*512 + n];
#pragma unroll
      for (int r = 0; r < 4; r++) acc[r] += xh[r*192 + k] * wv;
    }
#pragma unroll 8
    for (int k = 0; k < 128; k++) {
      float wv = Whht[k*512 + n];
#pragma unroll
      for (int r = 0; r < 4; r++) acc[r] += xh[r*192 + 64 + k] * wv;
    }
#pragma unroll
    for (int r = 0; r < 4; r++) gl[r*512 + n] = acc[r];
  }
  __syncthreads();
  {
    int r = tid >> 7, hh = tid & 127;
    float ig = gl[r*512 + hh],       fg = gl[r*512 + 128 + hh];
    float gg = gl[r*512 + 256 + hh], og = gl[r*512 + 384 + hh];
    ig = 1.f/(1.f+expf(-ig)); fg = 1.f/(1.f+expf(-fg));
    gg = tanhf(gg);           og = 1.f/(1.f+expf(-og));
    int row = b0 + r;
    float c2 = fg * cst[row*128 + hh] + ig * gg;
    float h2 = og * tanhf(c2);
    cst[row*128 + hh] = c2;
    hbuf[r*128 + hh] = h2;
    hcatB[(size_t)row*1152 + hh] = bf16bits(h2);
  }
  __syncthreads();
  if (tid < 128) {
    int r = tid >> 5, col = (tid >> 4) & 1, l16 = tid & 15;
    float s = 0.f;
    for (int k = l16; k < 128; k += 16) s += hbuf[r*128 + k] * W_h2p[k*2 + col];
#pragma unroll
    for (int off = 8; off > 0; off >>= 1) s += __shfl_xor(s, off);
    if (l16 == 0) {
      float rel = s + b_h2p[col];
      float old = lp[(b0+r)*2 + col];
      relS[r*2 + col] = rel;
      curS[r*2 + col] = old + rel;
      lp[(b0+r)*2 + col] = old + rel;
      pred[t*2048 + (b0+r)*2 + col] = rel;
    }
  }
  __syncthreads();
  if (tid < 256) {
    int r = tid >> 6, e = tid & 63;
    din[(b0+r)*64 + e] = relS[r*2]*W_emb[e] + relS[r*2+1]*W_emb[64+e] + b_emb[e];
  }
  {
    const int n = tid;
    float acc[4] = {0.f, 0.f, 0.f, 0.f};
#pragma unroll 4
    for (int k = 0; k < 128; k++) {
      float wv = W1b[k*512 + n];
#pragma unroll
      for (int r = 0; r < 4; r++) acc[r] += hbuf[r*128 + k] * wv;
    }
    float wc0 = Wc[n], wc1 = Wc[512+n], bcv = bc[n];
#pragma unroll
    for (int r = 0; r < 4; r++) {
      float pw = curS[r*2]*wc0 + curS[r*2+1]*wc1;
      PW[(size_t)(b0+r)*512 + n] = pw;
      Aa[(size_t)(b0+r)*512 + n] = acc[r] + pw + bcv;
    }
  }
}

// --- Pool GEMM v8 (R10-exact, best measured 44.6us): A-resident 128KB LDS +
// B staged in MFMA-fragment layout, double-buffered (2x16KB). One
// __syncthreads per k-step.
__global__ __launch_bounds__(512) void k_pool8(
    const float* __restrict__ Aa, const float* __restrict__ PW,
    const unsigned short* __restrict__ Wfrag, const float* __restrict__ bp2,
    unsigned short* __restrict__ hcatB) {
  const int bid = blockIdx.x;
  const int mt = (bid >> 3) & 7;
  const int g  = (bid & 7) + ((bid >> 6) << 3);
  const int tid = threadIdx.x, lane = tid & 63, w = tid >> 6;
  const int wr = w >> 2, wc = w & 3;     // 2m x 4n waves, wave tile 64m x 64n
  const int l15 = lane & 15, lhi = lane >> 4;
  __shared__ __align__(128) char lds[163840];
  char* As = lds;                 // [128 rows][1024B] swizzled
  char* B0 = lds + 131072;        // chunk buffer 0 [16 nb][1024B]
  char* B1 = lds + 131072 + 16384;

  // Build A tile (rows m = ii*32 + j, i = mt*4+ii): conflict-free wave rows.
  {
    const int ke = lane * 8;
#pragma unroll 4
    for (int rr = 0; rr < 16; rr++) {
      const int r = rr * 8 + w;
      const int j = r & 31, ii = r >> 5;
      const float* aRow = Aa + (size_t)(g*32 + j)*512 + ke;
      const float* pRow = PW + (size_t)(g*32 + mt*4 + ii)*512 + ke;
      float4 a0 = *(const float4*)aRow;
      float4 a1 = *(const float4*)(aRow + 4);
      float4 p0 = *(const float4*)pRow;
      float4 p1 = *(const float4*)(pRow + 4);
      bf16x8 y;
      y[0] = (__bf16)fmaxf(a0.x - p0.x, 0.f);
      y[1] = (__bf16)fmaxf(a0.y - p0.y, 0.f);
      y[2] = (__bf16)fmaxf(a0.z - p0.z, 0.f);
      y[3] = (__bf16)fmaxf(a0.w - p0.w, 0.f);
      y[4] = (__bf16)fmaxf(a1.x - p1.x, 0.f);
      y[5] = (__bf16)fmaxf(a1.y - p1.y, 0.f);
      y[6] = (__bf16)fmaxf(a1.z - p1.z, 0.f);
      y[7] = (__bf16)fmaxf(a1.w - p1.w, 0.f);
      *(bf16x8*)(As + SWZP(r*1024 + lane*16, r)) = y;
    }
  }

  const int u0 = tid, u1 = tid + 512;
  const size_t gfo0 = (size_t)((u0 >> 6) * 16) * 512 + (u0 & 63) * 8;
  const size_t gfo1 = (size_t)((u1 >> 6) * 16) * 512 + (u1 & 63) * 8;

  // prologue: chunk 0 -> B0; chunk 1 -> regs
  {
    u16x8 s0 = *(const u16x8*)(Wfrag + gfo0);
    u16x8 s1 = *(const u16x8*)(Wfrag + gfo1);
    *(u16x8*)(B0 + u0*16) = s0;
    *(u16x8*)(B0 + u1*16) = s1;
  }
  u16x8 r0, r1;
  {
    const size_t base = (size_t)512;  // q=1
    r0 = *(const u16x8*)(Wfrag + base + gfo0);
    r1 = *(const u16x8*)(Wfrag + base + gfo1);
  }
  __syncthreads();

  for (int nt = 0; nt < 4; nt++) {
    f32x4 acc[4][4] = {};
    for (int k0 = 0; k0 < 16; k0++) {
      const int q = nt*16 + k0;
      char* Bcur = (q & 1) ? B1 : B0;
      char* Bnxt = (q & 1) ? B0 : B1;
      if (q < 63) {  // write chunk q+1 (loaded at iter q-1 / prologue)
        *(u16x8*)(Bnxt + u0*16) = r0;
        *(u16x8*)(Bnxt + u1*16) = r1;
      }
      if (q < 62) {  // issue loads for chunk q+2
        const int q2 = q + 2;
        const size_t base = (size_t)((q2 >> 4) * 256 + (q2 & 15)) * 512;
        r0 = *(const u16x8*)(Wfrag + base + gfo0);
        r1 = *(const u16x8*)(Wfrag + base + gfo1);
      }
      bf16x8 af[4], bfr[4];
#pragma unroll
      for (int mf = 0; mf < 4; mf++) {
        const int row = wr*64 + mf*16 + l15;
        af[mf] = *(const bf16x8*)(As + SWZP(row*1024 + k0*64 + lhi*16, row));
      }
#pragma unroll
      for (int nf = 0; nf < 4; nf++)
        bfr[nf] = *(const bf16x8*)(Bcur + (wc*4 + nf)*1024 + lane*16);
#pragma unroll
      for (int mf = 0; mf < 4; mf++)
#pragma unroll
        for (int nf = 0; nf < 4; nf++)
          acc[mf][nf] = __builtin_amdgcn_mfma_f32_16x16x32_bf16(
              af[mf], bfr[nf], acc[mf][nf], 0, 0, 0);
      __syncthreads();
    }
    // epilogue: max over j, bias, relu -> hcatB pool columns
#pragma unroll
    for (int isub = 0; isub < 2; isub++)
#pragma unroll
      for (int nf = 0; nf < 4; nf++) {
        f32x4 v0 = acc[isub*2][nf], v1 = acc[isub*2 + 1][nf];
        float mx = fmaxf(fmaxf(fmaxf(v0[0], v0[1]), fmaxf(v0[2], v0[3])),
                         fmaxf(fmaxf(v1[0], v1[1]), fmaxf(v1[2], v1[3])));
        mx = fmaxf(mx, __shfl_xor(mx, 16));
        mx = fmaxf(mx, __shfl_xor(mx, 32));
        if (lane < 16) {
          const int n = nt*256 + wc*64 + nf*16 + lane;
          const int i = mt*4 + wr*2 + isub;
          hcatB[(size_t)(g*32 + i)*1152 + 128 + n] =
              bf16bits(fmaxf(mx + bp2[n], 0.f));
        }
      }
  }
}

// mid = relu(hcatB @ Wm1t^T + b_m1) -> bf16 midB.
// K-split-wave GEMM (R11): grid (16,16), 256 thr, 4 waves k-split.
__global__ __launch_bounds__(256) void k_m1k(
    const unsigned short* __restrict__ A, const unsigned short* __restrict__ Bw,
    const float* __restrict__ bias, unsigned short* __restrict__ outB) {
  const int nt = blockIdx.x, mt = blockIdx.y;
  const int tid = threadIdx.x, lane = tid & 63, w = tid >> 6;
  const int l15 = lane & 15, lhi = lane >> 4;
  __shared__ __align__(128) char lds[65536];  // buf b: A @ b*32768, B @ +16384
  const unsigned short* aSrc = A  + (size_t)(mt*64)*1152;
  const unsigned short* bSrc = Bw + (size_t)(nt*64)*1152;

  u16x8 rg[8];
#pragma unroll
  for (int p = 0; p < 8; p++) {
    const int u = tid + p*256;
    const int isB = u >> 10, v = u & 1023;
    const int row = v >> 4, slot = v & 15;
    u16x8 val = *(const u16x8*)((isB ? bSrc : aSrc) + (size_t)row*1152 + slot*8);
    *(u16x8*)(lds + isB*16384 + SWZP(row*256 + slot*16, row)) = val;
  }
#pragma unroll
  for (int p = 0; p < 8; p++) {
    const int u = tid + p*256;
    const int isB = u >> 10, v = u & 1023;
    const int row = v >> 4, slot = v & 15;
    rg[p] = *(const u16x8*)((isB ? bSrc : aSrc) + (size_t)row*1152 + 128 + slot*8);
  }
  __syncthreads();

  f32x4 acc[4][4] = {};
  for (int c = 0; c < 9; c++) {
    const int cur = (c & 1) * 32768;
    const int nxt = 32768 - cur;
    if (c < 8) {
#pragma unroll
      for (int p = 0; p < 8; p++) {
        const int u = tid + p*256;
        const int isB = u >> 10, v = u & 1023;
        const int row = v >> 4, slot = v & 15;
        *(u16x8*)(lds + nxt + isB*16384 + SWZP(row*256 + slot*16, row)) = rg[p];
      }
    }
    if (c < 7) {
#pragma unroll
      for (int p = 0; p < 8; p++) {
        const int u = tid + p*256;
        const int isB = u >> 10, v = u & 1023;
        const int row = v >> 4, slot = v & 15;
        rg[p] = *(const u16x8*)((isB ? bSrc : aSrc) + (size_t)row*1152 +
                                (c+2)*128 + slot*8);
      }
    }
    bf16x8 af[4], bf[4];
#pragma unroll
    for (int mf = 0; mf < 4; mf++) {
      const int row = mf*16 + l15;
      af[mf] = *(const bf16x8*)(lds + cur + SWZP(row*256 + w*64 + lhi*16, row));
    }
#pragma unroll
    for (int nf = 0; nf < 4; nf++) {
      const int row = nf*16 + l15;
      bf[nf] = *(const bf16x8*)(lds + cur + 16384 +
                                SWZP(row*256 + w*64 + lhi*16, row));
    }
#pragma unroll
    for (int mf = 0; mf < 4; mf++)
#pragma unroll
      for (int nf = 0; nf < 4; nf++)
        acc[mf][nf] = __builtin_amdgcn_mfma_f32_16x16x32_bf16(
            af[mf], bf[nf], acc[mf][nf], 0, 0, 0);
    __syncthreads();
  }

#pragma unroll
  for (int mf = 0; mf < 4; mf++)
#pragma unroll
    for (int nf = 0; nf < 4; nf++)
      *(f32x4*)(lds + w*16384 + (mf*4 + nf)*1024 + lane*16) = acc[mf][nf];
  __syncthreads();
#pragma unroll
  for (int pi = 0; pi < 4; pi++) {
    const int p = w*4 + pi;
    f32x4 s = *(const f32x4*)(lds + p*1024 + lane*16);
#pragma unroll
    for (int wv = 1; wv < 4; wv++) {
      f32x4 q = *(const f32x4*)(lds + wv*16384 + p*1024 + lane*16);
      s[0] += q[0]; s[1] += q[1]; s[2] += q[2]; s[3] += q[3];
    }
    const int col = nt*64 + (p & 3)*16 + l15;
    const float bv = bias[col];
#pragma unroll
    for (int r = 0; r < 4; r++) {
      const int row = mt*64 + (p >> 2)*16 + lhi*4 + r;
      outB[(size_t)row*1024 + col] = bf16bits(fmaxf(s[r] + bv, 0.f));
    }
  }
}

// h_dec = relu(midB @ Wm2tB^T + b_m2) fp32. K-split-wave (R11).
// At t==T_SEQ-1 also writes out (folds k_hfin).
__global__ __launch_bounds__(256) void k_m2k(
    const unsigned short* __restrict__ A, const unsigned short* __restrict__ Bw,
    const float* __restrict__ bias, float* __restrict__ hd,
    float* __restrict__ out, int last) {
  const int nt = blockIdx.x, mt = blockIdx.y;
  const int tid = threadIdx.x, lane = tid & 63, w = tid >> 6;
  const int l15 = lane & 15, lhi = lane >> 4;
  __shared__ __align__(128) char lds[49152];  // buf b @ b*24576: A 8KB, B 16KB
  const unsigned short* aSrc = A  + (size_t)(mt*32)*1024;
  const unsigned short* bSrc = Bw + (size_t)(nt*64)*1024;

  u16x8 rg[6];
#pragma unroll
  for (int p = 0; p < 6; p++) {
    const int u = tid + p*256;
    const int isB = (u >= 512);
    const int v = isB ? (u - 512) : u;
    const int row = v >> 4, slot = v & 15;
    u16x8 val = *(const u16x8*)((isB ? bSrc : aSrc) + (size_t)row*1024 + slot*8);
    *(u16x8*)(lds + isB*8192 + SWZP(row*256 + slot*16, row)) = val;
  }
#pragma unroll
  for (int p = 0; p < 6; p++) {
    const int u = tid + p*256;
    const int isB = (u >= 512);
    const int v = isB ? (u - 512) : u;
    const int row = v >> 4, slot = v & 15;
    rg[p] = *(const u16x8*)((isB ? bSrc : aSrc) + (size_t)row*1024 + 128 + slot*8);
  }
  __syncthreads();

  f32x4 acc[2][4] = {};
  for (int c = 0; c < 8; c++) {
    const int cur = (c & 1) * 24576;
    const int nxt = 24576 - cur;
    if (c < 7) {
#pragma unroll
      for (int p = 0; p < 6; p++) {
        const int u = tid + p*256;
        const int isB = (u >= 512);
        const int v = isB ? (u - 512) : u;
        const int row = v >> 4, slot = v & 15;
        *(u16x8*)(lds + nxt + isB*8192 + SWZP(row*256 + slot*16, row)) = rg[p];
      }
    }
    if (c < 6) {
#pragma unroll
      for (int p = 0; p < 6; p++) {
        const int u = tid + p*256;
        const int isB = (u >= 512);
        const int v = isB ? (u - 512) : u;
        const int row = v >> 4, slot = v & 15;
        rg[p] = *(const u16x8*)((isB ? bSrc : aSrc) + (size_t)row*1024 +
                                (c+2)*128 + slot*8);
      }
    }
    bf16x8 af[2], bf[4];
#pragma unroll
    for (int mf = 0; mf < 2; mf++) {
      const int row = mf*16 + l15;
      af[mf] = *(const bf16x8*)(lds + cur + SWZP(row*256 + w*64 + lhi*16, row));
    }
#pragma unroll
    for (int nf = 0; nf < 4; nf++) {
      const int row = nf*16 + l15;
      bf[nf] = *(const bf16x8*)(lds + cur + 8192 +
                                SWZP(row*256 + w*64 + lhi*16, row));
    }
#pragma unroll
    for (int mf = 0; mf < 2; mf++)
#pragma unroll
      for (int nf = 0; nf < 4; nf++)
        acc[mf][nf] = __builtin_amdgcn_mfma_f32_16x16x32_bf16(
            af[mf], bf[nf], acc[mf][nf], 0, 0, 0);
    __syncthreads();
  }

#pragma unroll
  for (int mf = 0; mf < 2; mf++)
#pragma unroll
    for (int nf = 0; nf < 4; nf++)
      *(f32x4*)(lds + w*8192 + (mf*4 + nf)*1024 + lane*16) = acc[mf][nf];
  __syncthreads();
#pragma unroll
  for (int pi = 0; pi < 2; pi++) {
    const int p = w*2 + pi;
    f32x4 s = *(const f32x4*)(lds + p*1024 + lane*16);
#pragma unroll
    for (int wv = 1; wv < 4; wv++) {
      f32x4 q = *(const f32x4*)(lds + wv*8192 + p*1024 + lane*16);
      s[0] += q[0]; s[1] += q[1]; s[2] += q[2]; s[3] += q[3];
    }
    const int col = nt*64 + (p & 3)*16 + l15;
    const float bv = bias[col];
#pragma unroll
    for (int r = 0; r < 4; r++) {
      const int row = mt*32 + (p >> 2)*16 + lhi*4 + r;
      float v = fmaxf(s[r] + bv, 0.f);
      hd[(size_t)row*128 + col] = v;
      if (last) out[24576 + (size_t)row*128 + col] = v;
    }
  }
}

extern "C" void kernel_launch(void* const* d_in, const int* in_sizes, int n_in,
                              void* d_out, int out_size, void* d_ws, size_t ws_size,
                              hipStream_t stream) {
  const float* last_pos = (const float*)d_in[0];
  const float* lpr      = (const float*)d_in[1];
  const float* dh       = (const float*)d_in[2];
  const float* dc       = (const float*)d_in[3];
  const float* W_emb = (const float*)d_in[5];
  const float* b_emb = (const float*)d_in[6];
  const float* W_ih  = (const float*)d_in[7];
  const float* b_ih  = (const float*)d_in[8];
  const float* W_hh  = (const float*)d_in[9];
  const float* b_hh  = (const float*)d_in[10];
  const float* W_h2p = (const float*)d_in[11];
  const float* b_h2p = (const float*)d_in[12];
  const float* W_sp  = (const float*)d_in[13];
  const float* b_sp  = (const float*)d_in[14];
  const float* W_pp1 = (const float*)d_in[15];
  const float* b_pp1 = (const float*)d_in[16];
  const float* W_pp2 = (const float*)d_in[17];
  const float* b_pp2 = (const float*)d_in[18];
  const float* W_m1  = (const float*)d_in[19];
  const float* b_m1  = (const float*)d_in[20];
  const float* W_m2  = (const float*)d_in[21];
  const float* b_m2  = (const float*)d_in[22];

  float* ws    = (float*)d_ws;
  float* lp    = ws + OFF_LP;
  float* din   = ws + OFF_DIN;
  float* cst   = ws + OFF_C;
  float* h_dec = ws + OFF_HDEC;
  float* Wc    = ws + OFF_WC;
  float* bc    = ws + OFF_BC;
  float* PW    = ws + OFF_PW;
  float* Aa    = ws + OFF_AA;
  unsigned short* Wp2t  = (unsigned short*)(ws + OFF_WP2T);
  unsigned short* Wm1t  = (unsigned short*)(ws + OFF_WM1T);
  unsigned short* hcatB = (unsigned short*)(ws + OFF_HCATB);
  unsigned short* Wm2tB = (unsigned short*)(ws + OFF_WM2TB);
  unsigned short* midB  = (unsigned short*)(ws + OFF_MIDB);
  float* Wiht  = ws + OFF_WIHT;
  float* Whht  = ws + OFF_WHHT;
  unsigned short* Wfrag = (unsigned short*)(ws + OFF_WFRAG);
  float* out   = (float*)d_out;

  k_setup<<<512, 256, 0, stream>>>(last_pos, lpr, dh, dc, W_emb, b_emb, lp, din, h_dec, cst);
  k_wc<<<2, 256, 0, stream>>>(W_sp, b_sp, W_pp1, b_pp1, Wc, bc);
  { dim3 gt(32, 16); k_tcvt<<<gt, 256, 0, stream>>>(W_pp2, Wp2t, 512, 1024); }
  { dim3 gt(32, 36); k_tcvt<<<gt, 256, 0, stream>>>(W_m1, Wm1t, 1152, 1024); }
  { dim3 gt(4, 32);  k_tcvt<<<gt, 256, 0, stream>>>(W_m2, Wm2tB, 1024, 128); }
  { dim3 gt(2, 16);  k_t32<<<gt, 256, 0, stream>>>(W_ih, Wiht, 512, 64); }
  { dim3 gt(4, 16);  k_t32<<<gt, 256, 0, stream>>>(W_hh, Whht, 512, 128); }
  k_frag<<<256, 256, 0, stream>>>(Wp2t, Wfrag);

  for (int t = 0; t < T_SEQ; t++) {
    k_step1<<<256, 512, 0, stream>>>(din, h_dec, cst, hcatB, lp, out,
                                     Wiht, b_ih, Whht, b_hh, W_h2p, b_h2p,
                                     W_emb, b_emb, W_pp1 + 64*512, Wc, bc,
                                     PW, Aa, t);
    k_pool8<<<256, 512, 0, stream>>>(Aa, PW, Wfrag, b_pp2, hcatB);
    { dim3 gm(16, 16); k_m1k<<<gm, 256, 0, stream>>>(hcatB, Wm1t, b_m1, midB); }
    { dim3 gm(2, 32);  k_m2k<<<gm, 256, 0, stream>>>(midB, Wm2tB, b_m2, h_dec,
                                                     out, t == T_SEQ-1); }
  }
}